// Round 9
// baseline (231.502 us; speedup 1.0000x reference)
//
#include <hip/hip_runtime.h>
#include <hip/hip_bf16.h>

typedef __attribute__((ext_vector_type(4))) float f32x4;
typedef __attribute__((ext_vector_type(8))) short bf16x8;   // 8 bf16 = 4 VGPRs
typedef unsigned short u16;
typedef __attribute__((ext_vector_type(4))) u16 u16x4;

// Problem constants
// g [2,2048,1024] f32 ; Wq/Wk [12,64,1024] f32 ; Whn [4096,1024] f32 ; out = scalar f32

// workspace layout (bytes)
#define OFF_GB    ((size_t)0)                    // g bf16      [4096][1024]  8388608
#define OFF_WQB   ((size_t)8388608)              // (beta*log2e)*Wq bf16 [768][1024]
#define OFF_WKB   ((size_t)(8388608+1572864))    // Wk bf16      [768][1024]
#define OFF_WHNB  ((size_t)(8388608+2*1572864))  // Whn bf16    [4096][1024]  8388608
#define OFF_QB    (OFF_WHNB + 8388608)           // q bf16 [24][2048][64] per-head
#define OFF_KB    (OFF_QB + 6291456)             // k bf16 [24][2048][64] per-head

__device__ __forceinline__ u16 f2bf(float f) {
  union { float f; unsigned u; } x; x.f = f;
  unsigned u = x.u;
  u += 0x7fffu + ((u >> 16) & 1u);   // RNE
  return (u16)(u >> 16);
}

// ---------------- fused f32 -> bf16 conversion (beta*log2e folded into Wq) ----------------
__global__ __launch_bounds__(256) void convert_all(
    const float* __restrict__ g, const float* __restrict__ wq,
    const float* __restrict__ wk, const float* __restrict__ whn,
    u16* __restrict__ gB, u16* __restrict__ wqB, u16* __restrict__ wkB, u16* __restrict__ whnB)
{
  const int NG = 1048576;   // 4194304/4 float4 quads
  const int NW = 196608;    // 786432/4
  const int total = NG + 2 * NW + NG;
  for (int i = blockIdx.x * blockDim.x + threadIdx.x; i < total; i += gridDim.x * blockDim.x) {
    const float4* src; u16* dst; int j; float scale = 1.0f;
    if (i < NG)              { src = (const float4*)g;   dst = gB;   j = i; }
    else if (i < NG + NW)    { src = (const float4*)wq;  dst = wqB;  j = i - NG;
                               scale = 0.125f * 1.44269504089f; }   // beta * log2(e)
    else if (i < NG + 2*NW)  { src = (const float4*)wk;  dst = wkB;  j = i - NG - NW; }
    else                     { src = (const float4*)whn; dst = whnB; j = i - NG - 2*NW; }
    float4 v = src[j];
    u16x4 o;
    o.x = f2bf(v.x * scale); o.y = f2bf(v.y * scale);
    o.z = f2bf(v.z * scale); o.w = f2bf(v.w * scale);
    *(u16x4*)(dst + (size_t)j * 4) = o;
  }
}

// ---------------- 128x128 tile GEMM (m97 structure), q/k projection ----------------
// XCD-chunked 1D grid (384 blocks): xcd = bid&7 owns bm in [ (xcd>>1)*8, +8 ),
// bn in [ (xcd&1)*6, +6 ) -> per-XCD L2 set = 2MB A + 1.5MB B < 4MB.
// bn<6 -> Wq->qB, else Wk->kB; store bf16 into per-head layout [z][n][64]
__global__ __launch_bounds__(256) void gemm_bt(
    const u16* __restrict__ A, const u16* __restrict__ B0, const u16* __restrict__ B1,
    u16* __restrict__ C0, u16* __restrict__ C1, int K)
{
  __shared__ u16 lA[128 * 64];
  __shared__ u16 lB[128 * 64];
  const int tid = threadIdx.x;
  const int lane = tid & 63;
  const int w = tid >> 6;          // wave 0..3
  const int bid = blockIdx.x;
  const int xcd = bid & 7, idx = bid >> 3;          // idx 0..47
  const int bm = ((xcd >> 1) << 3) + (idx & 7);     // 0..31
  const int bn = (xcd & 1) * 6 + (idx >> 3);        // 0..11

  const u16* Bp; u16* Cp; int bcol0;
  if (bn < 6) { Bp = B0; Cp = C0; bcol0 = bn * 128; }
  else        { Bp = B1; Cp = C1; bcol0 = (bn - 6) * 128; }
  const int arow0 = bm * 128;
  const int wr = w >> 1, wc = w & 1;
  const int l15 = lane & 15, lg = lane >> 4;

  f32x4 acc[4][4];
  const f32x4 zz = {0.f, 0.f, 0.f, 0.f};
#pragma unroll
  for (int m = 0; m < 4; m++)
#pragma unroll
    for (int n = 0; n < 4; n++) acc[m][n] = zz;

#define STAGE(KT) do {                                                                     \
    _Pragma("unroll")                                                                      \
    for (int i = 0; i < 4; i++) {                                                          \
      int rloc = w * 32 + i * 8 + (lane >> 3);                                             \
      int cb   = (((lane & 7) ^ (rloc & 7)) << 4);                                         \
      const char* srcA = (const char*)A + (((size_t)(arow0 + rloc)) * K + (KT) * 64) * 2 + cb; \
      __builtin_amdgcn_global_load_lds((const __attribute__((address_space(1))) void*)srcA, \
          (__attribute__((address_space(3))) void*)((char*)lA + (w * 32 + i * 8) * 128), 16, 0, 0); \
      const char* srcB = (const char*)Bp + (((size_t)(bcol0 + rloc)) * K + (KT) * 64) * 2 + cb; \
      __builtin_amdgcn_global_load_lds((const __attribute__((address_space(1))) void*)srcB, \
          (__attribute__((address_space(3))) void*)((char*)lB + (w * 32 + i * 8) * 128), 16, 0, 0); \
    }                                                                                      \
  } while (0)

  STAGE(0);
  const int nkt = K / 64;
  for (int kt = 0; kt < nkt; ++kt) {
    __syncthreads();
    bf16x8 a0[4], a1[4], b0[4], b1[4];
#pragma unroll
    for (int m = 0; m < 4; m++) {
      int row = wr * 64 + m * 16 + l15;
      const char* base = (const char*)lA + row * 128;
      int sw = (row & 7) << 4;
      a0[m] = *(const bf16x8*)(base + ((lg * 16) ^ sw));
      a1[m] = *(const bf16x8*)(base + ((64 + lg * 16) ^ sw));
    }
#pragma unroll
    for (int n = 0; n < 4; n++) {
      int row = wc * 64 + n * 16 + l15;
      const char* base = (const char*)lB + row * 128;
      int sw = (row & 7) << 4;
      b0[n] = *(const bf16x8*)(base + ((lg * 16) ^ sw));
      b1[n] = *(const bf16x8*)(base + ((64 + lg * 16) ^ sw));
    }
    __syncthreads();
    if (kt + 1 < nkt) STAGE(kt + 1);
#pragma unroll
    for (int m = 0; m < 4; m++)
#pragma unroll
      for (int n = 0; n < 4; n++) {
        acc[m][n] = __builtin_amdgcn_mfma_f32_16x16x32_bf16(a0[m], b0[n], acc[m][n], 0, 0, 0);
        acc[m][n] = __builtin_amdgcn_mfma_f32_16x16x32_bf16(a1[m], b1[n], acc[m][n], 0, 0, 0);
      }
  }
  // C/D layout (m89-verified): col = lane&15, row = (lane>>4)*4 + reg
  // per-head dst: row = b*2048+nn, col = h*64+d  ->  ((b*12+h)*2048 + nn)*64 + d
#pragma unroll
  for (int m = 0; m < 4; m++)
#pragma unroll
    for (int n = 0; n < 4; n++)
#pragma unroll
      for (int r = 0; r < 4; r++) {
        int row = arow0 + wr * 64 + m * 16 + lg * 4 + r;
        int col = bcol0 + wc * 64 + n * 16 + l15;
        size_t dst = ((((size_t)(row >> 11) * 12 + (col >> 6)) << 11) + (row & 2047)) * 64 + (col & 63);
        Cp[dst] = f2bf(acc[m][n][r]);
      }
#undef STAGE
}

// ---------------- Hopfield energy: m97 128x128/BK=64 structure + XCD chunking ----------------
// grid = 1024 blocks = EXACTLY 4 blocks/CU co-resident (LDS 32KB x4 = 128KB, VGPR ~84
// -> 16 waves/CU). Inter-block overlap hides the 2-barrier-per-tile drain (m114).
// XCD chunk: xcd = bid&7 owns 8bm x 16bn of the 32x32 tile grid; per-K-tile per-XCD
// staging slice = (8+16)x128 rows x 128B = 384KB -> L2-resident (round-7-verified FETCH drop).
// 128-B LDS rows + (row&7)<<4 XOR swizzle = 0 bank conflicts (verified rounds 2-7;
// round-8 BK=32/64-B-row variant proved col-XOR needs >=128-B pitch - 4.2M conflicts).
__global__ __launch_bounds__(256) void hop_gemm(
    const u16* __restrict__ A, const u16* __restrict__ Bm, float* __restrict__ out)
{
  __shared__ u16 lA[128 * 64];
  __shared__ u16 lB[128 * 64];
  const int tid = threadIdx.x;
  const int lane = tid & 63;
  const int w = tid >> 6;          // wave 0..3
  const int bid = blockIdx.x;
  const int xcd = bid & 7, idx = bid >> 3;            // idx 0..127
  const int bm = ((xcd >> 1) << 3) + (idx & 7);       // 0..31
  const int bn = ((xcd & 1) << 4) + (idx >> 3);       // 0..31
  const int arow0 = bm * 128;
  const int bcol0 = bn * 128;
  const int wr = w >> 1, wc = w & 1;
  const int l15 = lane & 15, lg = lane >> 4;
  constexpr int K = 1024;

  f32x4 acc[4][4];
  const f32x4 zz = {0.f, 0.f, 0.f, 0.f};
#pragma unroll
  for (int m = 0; m < 4; m++)
#pragma unroll
    for (int n = 0; n < 4; n++) acc[m][n] = zz;

#define HSTAGE(KT) do {                                                                    \
    _Pragma("unroll")                                                                      \
    for (int i = 0; i < 4; i++) {                                                          \
      int rloc = w * 32 + i * 8 + (lane >> 3);                                             \
      int cb   = (((lane & 7) ^ (rloc & 7)) << 4);                                         \
      const char* srcA = (const char*)A + (((size_t)(arow0 + rloc)) * K + (KT) * 64) * 2 + cb; \
      __builtin_amdgcn_global_load_lds((const __attribute__((address_space(1))) void*)srcA, \
          (__attribute__((address_space(3))) void*)((char*)lA + (w * 32 + i * 8) * 128), 16, 0, 0); \
      const char* srcB = (const char*)Bm + (((size_t)(bcol0 + rloc)) * K + (KT) * 64) * 2 + cb; \
      __builtin_amdgcn_global_load_lds((const __attribute__((address_space(1))) void*)srcB, \
          (__attribute__((address_space(3))) void*)((char*)lB + (w * 32 + i * 8) * 128), 16, 0, 0); \
    }                                                                                      \
  } while (0)

  HSTAGE(0);
  const int nkt = K / 64;   // 16
  for (int kt = 0; kt < nkt; ++kt) {
    __syncthreads();   // staging of tile kt complete (vmcnt drain)
    bf16x8 a0[4], a1[4], b0[4], b1[4];
#pragma unroll
    for (int m = 0; m < 4; m++) {
      int row = wr * 64 + m * 16 + l15;
      const char* base = (const char*)lA + row * 128;
      int sw = (row & 7) << 4;
      a0[m] = *(const bf16x8*)(base + ((lg * 16) ^ sw));
      a1[m] = *(const bf16x8*)(base + ((64 + lg * 16) ^ sw));
    }
#pragma unroll
    for (int n = 0; n < 4; n++) {
      int row = wc * 64 + n * 16 + l15;
      const char* base = (const char*)lB + row * 128;
      int sw = (row & 7) << 4;
      b0[n] = *(const bf16x8*)(base + ((lg * 16) ^ sw));
      b1[n] = *(const bf16x8*)(base + ((64 + lg * 16) ^ sw));
    }
    __syncthreads();   // all reads landed; LDS free for restage
    if (kt + 1 < nkt) HSTAGE(kt + 1);   // overlap next staging with MFMA
#pragma unroll
    for (int m = 0; m < 4; m++)
#pragma unroll
      for (int n = 0; n < 4; n++) {
        acc[m][n] = __builtin_amdgcn_mfma_f32_16x16x32_bf16(a0[m], b0[n], acc[m][n], 0, 0, 0);
        acc[m][n] = __builtin_amdgcn_mfma_f32_16x16x32_bf16(a1[m], b1[n], acc[m][n], 0, 0, 0);
      }
  }
#undef HSTAGE

  // epilogue: -0.5 * sum(relu(c)^2), wave-reduce, one atomic per wave
  float loc = 0.f;
#pragma unroll
  for (int m = 0; m < 4; m++)
#pragma unroll
    for (int n = 0; n < 4; n++)
#pragma unroll
      for (int r = 0; r < 4; r++) {
        float v = acc[m][n][r];
        loc += (v > 0.f) ? v * v : 0.f;
      }
#pragma unroll
  for (int mask = 32; mask; mask >>= 1) loc += __shfl_xor(loc, mask, 64);
  if (lane == 0) atomicAdd(out, -0.5f * loc);
}

// ---------------- scores + logsumexp: LDS-staged, XCD-local, 3-deep ring ----------------
// grid (z=24, qt=32): linear block id = qt*24 + z, 24 % 8 == 0 -> XCD = z % 8.
__global__ __launch_bounds__(256) void scores_lse(
    const u16* __restrict__ qB, const u16* __restrict__ kB, float* __restrict__ out)
{
  __shared__ __align__(16) u16 kbuf[3][128 * 64];   // 3 x 16KB ring
  const int z  = blockIdx.x;          // b*12+h
  const int qt = blockIdx.y;
  const int tid = threadIdx.x, lane = tid & 63, w = tid >> 6;
  const int l15 = lane & 15, lg = lane >> 4;

  // q fragments in registers (A operand: row = lane&15 = q-row within the wave's 16)
  const u16* qp = qB + ((size_t)z * 2048 + qt * 64 + w * 16 + l15) * 64 + lg * 8;
  bf16x8 qf0 = *(const bf16x8*)qp;          // dims 0..31 slice
  bf16x8 qf1 = *(const bf16x8*)(qp + 32);   // dims 32..63 slice

#define KSTAGE(KB, BUF) do {                                                               \
    _Pragma("unroll")                                                                      \
    for (int i = 0; i < 4; i++) {                                                          \
      int rloc = i * 32 + w * 8 + (lane >> 3);                                             \
      int cb   = (((lane & 7) ^ (rloc & 7)) << 4);                                         \
      const char* src = (const char*)kB + ((size_t)z * 2048 + (KB) * 128 + rloc) * 128 + cb; \
      __builtin_amdgcn_global_load_lds((const __attribute__((address_space(1))) void*)src,  \
          (__attribute__((address_space(3))) void*)((char*)kbuf[(BUF)] + rloc * 128 + (lane & 7) * 16), 16, 0, 0); \
    }                                                                                      \
  } while (0)

  f32x4 sacc = {0.f, 0.f, 0.f, 0.f};   // reg r: q-row lg*4+r, key-col l15
  const f32x4 zz = {0.f, 0.f, 0.f, 0.f};

  KSTAGE(0, 0);
  KSTAGE(1, 1);
  asm volatile("s_waitcnt vmcnt(4)" ::: "memory");   // tile0 landed; tile1 in flight
  __builtin_amdgcn_s_barrier();
  __builtin_amdgcn_sched_barrier(0);

  const int NKB = 16;   // 2048 / 128
  for (int kb = 0; kb < NKB; ++kb) {
    // issue prefetch of kb+2 first (into the slot consumed at kb-1): max overlap
    if (kb + 2 < NKB) KSTAGE(kb + 2, (kb + 2) % 3);
    const char* cur = (const char*)kbuf[kb % 3];
#pragma unroll
    for (int g2 = 0; g2 < 8; ++g2) {
      int row = g2 * 16 + l15;
      const char* base = cur + row * 128;
      int sw = (row & 7) << 4;
      bf16x8 b0 = *(const bf16x8*)(base + ((lg * 16) ^ sw));
      bf16x8 b1 = *(const bf16x8*)(base + ((64 + lg * 16) ^ sw));
      f32x4 s = zz;
      s = __builtin_amdgcn_mfma_f32_16x16x32_bf16(qf0, b0, s, 0, 0, 0);
      s = __builtin_amdgcn_mfma_f32_16x16x32_bf16(qf1, b1, s, 0, 0, 0);
      sacc[0] += __builtin_amdgcn_exp2f(s[0]);
      sacc[1] += __builtin_amdgcn_exp2f(s[1]);
      sacc[2] += __builtin_amdgcn_exp2f(s[2]);
      sacc[3] += __builtin_amdgcn_exp2f(s[3]);
    }
    if (kb + 1 < NKB) {
      if (kb + 2 < NKB) asm volatile("s_waitcnt vmcnt(4)" ::: "memory");  // kb+1 done, kb+2 in flight
      else              asm volatile("s_waitcnt vmcnt(0)" ::: "memory");  // last stage done
      __builtin_amdgcn_s_barrier();
      __builtin_amdgcn_sched_barrier(0);
    }
  }
#undef KSTAGE

  // reduce over the 16 key-columns (lanes sharing lg)
#pragma unroll
  for (int mask = 8; mask; mask >>= 1) {
    sacc[0] += __shfl_xor(sacc[0], mask, 64);
    sacc[1] += __shfl_xor(sacc[1], mask, 64);
    sacc[2] += __shfl_xor(sacc[2], mask, 64);
    sacc[3] += __shfl_xor(sacc[3], mask, 64);
  }
  float part = 0.f;
  if (l15 == 0) {
    // v_log_f32 is natively log2
    part = __builtin_amdgcn_logf(sacc[0]) + __builtin_amdgcn_logf(sacc[1]) +
           __builtin_amdgcn_logf(sacc[2]) + __builtin_amdgcn_logf(sacc[3]);
  }
  part += __shfl_xor(part, 16, 64);
  part += __shfl_xor(part, 32, 64);
  // e_attn = -(1/beta)*sum(ln(sumexp)) = -8*ln2*sum(log2(sum2exp))
  if (lane == 0) atomicAdd(out, -5.5451774444795625f * part);
}

extern "C" void kernel_launch(void* const* d_in, const int* in_sizes, int n_in,
                              void* d_out, int out_size, void* d_ws, size_t ws_size,
                              hipStream_t stream)
{
  const float* g   = (const float*)d_in[0];
  const float* Wq  = (const float*)d_in[1];
  const float* Wk  = (const float*)d_in[2];
  const float* Whn = (const float*)d_in[3];
  float* out = (float*)d_out;
  char* ws = (char*)d_ws;

  u16* gB   = (u16*)(ws + OFF_GB);
  u16* wqB  = (u16*)(ws + OFF_WQB);
  u16* wkB  = (u16*)(ws + OFF_WKB);
  u16* whnB = (u16*)(ws + OFF_WHNB);
  u16* qB   = (u16*)(ws + OFF_QB);
  u16* kB   = (u16*)(ws + OFF_KB);

  (void)hipMemsetAsync(out, 0, sizeof(float), stream);

  convert_all<<<2048, 256, 0, stream>>>(g, Wq, Wk, Whn, gB, wqB, wkB, whnB);
  // q and k projections (XCD-chunked 1D grid: bn 0..5 -> q, 6..11 -> k)
  gemm_bt<<<384, 256, 0, stream>>>(gB, wqB, wkB, qB, kB, 1024);
  // Hopfield energy: m97 128x128 structure, 1024 blocks = 4/CU, XCD-chunked
  hop_gemm<<<1024, 256, 0, stream>>>(gB, whnB, out);
  // attention logsumexp (LDS-staged, XCD-local, 3-deep ring)
  scores_lse<<<dim3(24, 32), 256, 0, stream>>>(qB, kB, out);
}

// Round 10
// 198.675 us; speedup vs baseline: 1.1652x; 1.1652x over previous
//
#include <hip/hip_runtime.h>
#include <hip/hip_bf16.h>

typedef __attribute__((ext_vector_type(4))) float f32x4;
typedef __attribute__((ext_vector_type(8))) short bf16x8;   // 8 bf16 = 4 VGPRs
typedef unsigned short u16;
typedef __attribute__((ext_vector_type(4))) u16 u16x4;

// Problem constants
// g [2,2048,1024] f32 ; Wq/Wk [12,64,1024] f32 ; Whn [4096,1024] f32 ; out = scalar f32

// workspace layout (bytes)
#define OFF_GB    ((size_t)0)                    // g bf16      [4096][1024]  8388608
#define OFF_WQB   ((size_t)8388608)              // (beta*log2e)*Wq bf16 [768][1024]
#define OFF_WKB   ((size_t)(8388608+1572864))    // Wk bf16      [768][1024]
#define OFF_WHNB  ((size_t)(8388608+2*1572864))  // Whn bf16    [4096][1024]  8388608
#define OFF_QB    (OFF_WHNB + 8388608)           // q bf16 [24][2048][64] per-head
#define OFF_KB    (OFF_QB + 6291456)             // k bf16 [24][2048][64] per-head
#define OFF_ROWSUM (OFF_KB + 6291456)            // f32 [49152] rowsum partials

__device__ __forceinline__ u16 f2bf(float f) {
  union { float f; unsigned u; } x; x.f = f;
  unsigned u = x.u;
  u += 0x7fffu + ((u >> 16) & 1u);   // RNE
  return (u16)(u >> 16);
}

// ---------------- fused f32 -> bf16 conversion (beta*log2e folded into Wq) ----------------
__global__ __launch_bounds__(256) void convert_all(
    const float* __restrict__ g, const float* __restrict__ wq,
    const float* __restrict__ wk, const float* __restrict__ whn,
    u16* __restrict__ gB, u16* __restrict__ wqB, u16* __restrict__ wkB, u16* __restrict__ whnB)
{
  const int NG = 1048576;   // 4194304/4 float4 quads
  const int NW = 196608;    // 786432/4
  const int total = NG + 2 * NW + NG;
  for (int i = blockIdx.x * blockDim.x + threadIdx.x; i < total; i += gridDim.x * blockDim.x) {
    const float4* src; u16* dst; int j; float scale = 1.0f;
    if (i < NG)              { src = (const float4*)g;   dst = gB;   j = i; }
    else if (i < NG + NW)    { src = (const float4*)wq;  dst = wqB;  j = i - NG;
                               scale = 0.125f * 1.44269504089f; }   // beta * log2(e)
    else if (i < NG + 2*NW)  { src = (const float4*)wk;  dst = wkB;  j = i - NG - NW; }
    else                     { src = (const float4*)whn; dst = whnB; j = i - NG - 2*NW; }
    float4 v = src[j];
    u16x4 o;
    o.x = f2bf(v.x * scale); o.y = f2bf(v.y * scale);
    o.z = f2bf(v.z * scale); o.w = f2bf(v.w * scale);
    *(u16x4*)(dst + (size_t)j * 4) = o;
  }
}

// ---------------- 128x128 tile GEMM (m97 structure), q/k projection ----------------
// XCD-chunked 1D grid (384 blocks): xcd = bid&7 owns bm in [ (xcd>>1)*8, +8 ),
// bn in [ (xcd&1)*6, +6 ) -> per-XCD L2 set = 2MB A + 1.5MB B < 4MB.
// bn<6 -> Wq->qB, else Wk->kB; store bf16 into per-head layout [z][n][64]
__global__ __launch_bounds__(256) void gemm_bt(
    const u16* __restrict__ A, const u16* __restrict__ B0, const u16* __restrict__ B1,
    u16* __restrict__ C0, u16* __restrict__ C1, int K)
{
  __shared__ u16 lA[128 * 64];
  __shared__ u16 lB[128 * 64];
  const int tid = threadIdx.x;
  const int lane = tid & 63;
  const int w = tid >> 6;          // wave 0..3
  const int bid = blockIdx.x;
  const int xcd = bid & 7, idx = bid >> 3;          // idx 0..47
  const int bm = ((xcd >> 1) << 3) + (idx & 7);     // 0..31
  const int bn = (xcd & 1) * 6 + (idx >> 3);        // 0..11

  const u16* Bp; u16* Cp; int bcol0;
  if (bn < 6) { Bp = B0; Cp = C0; bcol0 = bn * 128; }
  else        { Bp = B1; Cp = C1; bcol0 = (bn - 6) * 128; }
  const int arow0 = bm * 128;
  const int wr = w >> 1, wc = w & 1;
  const int l15 = lane & 15, lg = lane >> 4;

  f32x4 acc[4][4];
  const f32x4 zz = {0.f, 0.f, 0.f, 0.f};
#pragma unroll
  for (int m = 0; m < 4; m++)
#pragma unroll
    for (int n = 0; n < 4; n++) acc[m][n] = zz;

#define STAGE(KT) do {                                                                     \
    _Pragma("unroll")                                                                      \
    for (int i = 0; i < 4; i++) {                                                          \
      int rloc = w * 32 + i * 8 + (lane >> 3);                                             \
      int cb   = (((lane & 7) ^ (rloc & 7)) << 4);                                         \
      const char* srcA = (const char*)A + (((size_t)(arow0 + rloc)) * K + (KT) * 64) * 2 + cb; \
      __builtin_amdgcn_global_load_lds((const __attribute__((address_space(1))) void*)srcA, \
          (__attribute__((address_space(3))) void*)((char*)lA + (w * 32 + i * 8) * 128), 16, 0, 0); \
      const char* srcB = (const char*)Bp + (((size_t)(bcol0 + rloc)) * K + (KT) * 64) * 2 + cb; \
      __builtin_amdgcn_global_load_lds((const __attribute__((address_space(1))) void*)srcB, \
          (__attribute__((address_space(3))) void*)((char*)lB + (w * 32 + i * 8) * 128), 16, 0, 0); \
    }                                                                                      \
  } while (0)

  STAGE(0);
  const int nkt = K / 64;
  for (int kt = 0; kt < nkt; ++kt) {
    __syncthreads();
    bf16x8 a0[4], a1[4], b0[4], b1[4];
#pragma unroll
    for (int m = 0; m < 4; m++) {
      int row = wr * 64 + m * 16 + l15;
      const char* base = (const char*)lA + row * 128;
      int sw = (row & 7) << 4;
      a0[m] = *(const bf16x8*)(base + ((lg * 16) ^ sw));
      a1[m] = *(const bf16x8*)(base + ((64 + lg * 16) ^ sw));
    }
#pragma unroll
    for (int n = 0; n < 4; n++) {
      int row = wc * 64 + n * 16 + l15;
      const char* base = (const char*)lB + row * 128;
      int sw = (row & 7) << 4;
      b0[n] = *(const bf16x8*)(base + ((lg * 16) ^ sw));
      b1[n] = *(const bf16x8*)(base + ((64 + lg * 16) ^ sw));
    }
    __syncthreads();
    if (kt + 1 < nkt) STAGE(kt + 1);
#pragma unroll
    for (int m = 0; m < 4; m++)
#pragma unroll
      for (int n = 0; n < 4; n++) {
        acc[m][n] = __builtin_amdgcn_mfma_f32_16x16x32_bf16(a0[m], b0[n], acc[m][n], 0, 0, 0);
        acc[m][n] = __builtin_amdgcn_mfma_f32_16x16x32_bf16(a1[m], b1[n], acc[m][n], 0, 0, 0);
      }
  }
  // C/D layout (m89-verified): col = lane&15, row = (lane>>4)*4 + reg
  // per-head dst: row = b*2048+nn, col = h*64+d  ->  ((b*12+h)*2048 + nn)*64 + d
#pragma unroll
  for (int m = 0; m < 4; m++)
#pragma unroll
    for (int n = 0; n < 4; n++)
#pragma unroll
      for (int r = 0; r < 4; r++) {
        int row = arow0 + wr * 64 + m * 16 + lg * 4 + r;
        int col = bcol0 + wc * 64 + n * 16 + l15;
        size_t dst = ((((size_t)(row >> 11) * 12 + (col >> 6)) << 11) + (row & 2047)) * 64 + (col & 63);
        Cp[dst] = f2bf(acc[m][n][r]);
      }
#undef STAGE
}

// ---------------- Hopfield energy: 256x256-tile 8-phase GEMM (R7 best: 59.6us) ----------------
// XCD-chunked 1D grid (256 blocks): xcd = bid&7 owns a contiguous 4bm x 8bn chunk.
__global__ __launch_bounds__(512, 2) void hop_gemm8(
    const u16* __restrict__ A, const u16* __restrict__ Bm, float* __restrict__ out)
{
  __shared__ __align__(16) u16 lds[2][2][2][128][64];   // [buf][mat][half][row][col]
  const int tid = threadIdx.x;
  const int lane = tid & 63, w = tid >> 6;
  const int wr = w >> 2, wc = w & 3;
  const int l15 = lane & 15, lg = lane >> 4;
  const int bid = blockIdx.x;
  const int xcd = bid & 7, idx = bid >> 3;            // idx 0..31
  const int am0 = (((xcd >> 1) << 2) + (idx & 3)) * 256;   // bm 0..15
  const int bn0 = (((xcd & 1) << 3) + (idx >> 2)) * 256;   // bn 0..15
  constexpr int nkt = 16;   // K = 1024, BK = 64

  f32x4 acc[8][4];
  const f32x4 zz = {0.f, 0.f, 0.f, 0.f};
#pragma unroll
  for (int i = 0; i < 8; i++)
#pragma unroll
    for (int j = 0; j < 4; j++) acc[i][j] = zz;

#define HSTAGE(KT, MAT, H) do {                                                            \
    const u16* s_ = (MAT) ? Bm : A;                                                        \
    int rb_ = ((MAT) ? bn0 : am0) + (H) * 128;                                             \
    char* d0_ = (char*)&lds[(KT) & 1][(MAT)][(H)][0][0];                                   \
    _Pragma("unroll")                                                                      \
    for (int q_ = 0; q_ < 2; q_++) {                                                       \
      int r_ = q_ * 64 + (tid >> 3);                                                       \
      int cb_ = ((tid & 7) * 16) ^ ((r_ & 7) << 4);                                        \
      const char* g_ = (const char*)s_ + (size_t)(rb_ + r_) * 2048 + (KT) * 128 + cb_;     \
      __builtin_amdgcn_global_load_lds((const __attribute__((address_space(1))) void*)g_,  \
          (__attribute__((address_space(3))) void*)(d0_ + q_ * 8192 + tid * 16), 16, 0, 0);\
    }                                                                                      \
  } while (0)

#define LDA_F(DST, P, I, S) do {                                                           \
    int rh_ = ((I) & 3) * 32 + wr * 16 + l15;                                              \
    const char* b_ = (const char*)&lds[(P)][0][(I) >> 2][0][0] + rh_ * 128;                \
    DST = *(const bf16x8*)(b_ + (((S) * 64 + lg * 16) ^ ((rh_ & 7) << 4)));                \
  } while (0)
#define LDB_F(DST, P, J, S) do {                                                           \
    int rh_ = ((J) & 1) * 64 + wc * 16 + l15;                                              \
    const char* b_ = (const char*)&lds[(P)][1][(J) >> 1][0][0] + rh_ * 128;                \
    DST = *(const bf16x8*)(b_ + (((S) * 64 + lg * 16) ^ ((rh_ & 7) << 4)));                \
  } while (0)

  // prologue: tile0 all 4 halves, tile1 first 3 halves -> 14 loads; drain to 6 (tile0 done)
  HSTAGE(0, 0, 0); HSTAGE(0, 1, 0); HSTAGE(0, 1, 1); HSTAGE(0, 0, 1);
  HSTAGE(1, 0, 0); HSTAGE(1, 1, 0); HSTAGE(1, 1, 1);
  asm volatile("s_waitcnt vmcnt(6)" ::: "memory");
  __builtin_amdgcn_s_barrier();

  bf16x8 af[4][2], bf[4][2];

#pragma unroll 2
  for (int t = 0; t < nkt; ++t) {
    const int p = t & 1;
    // ---- phase 0: ds_read A-h0 (m0-3) + B-h0 (n0-1); stage A-h1(t+1) ----
#pragma unroll
    for (int m = 0; m < 4; m++) { LDA_F(af[m][0], p, m, 0); LDA_F(af[m][1], p, m, 1); }
#pragma unroll
    for (int n = 0; n < 2; n++) { LDB_F(bf[n][0], p, n, 0); LDB_F(bf[n][1], p, n, 1); }
    if (t + 1 < nkt) HSTAGE(t + 1, 0, 1);
    __builtin_amdgcn_s_barrier();
    __builtin_amdgcn_s_setprio(1);
#pragma unroll
    for (int m = 0; m < 4; m++)
#pragma unroll
      for (int n = 0; n < 2; n++) {
        acc[m][n] = __builtin_amdgcn_mfma_f32_16x16x32_bf16(af[m][0], bf[n][0], acc[m][n], 0, 0, 0);
        acc[m][n] = __builtin_amdgcn_mfma_f32_16x16x32_bf16(af[m][1], bf[n][1], acc[m][n], 0, 0, 0);
      }
    __builtin_amdgcn_s_setprio(0);
    __builtin_amdgcn_s_barrier();
    // ---- phase 1: ds_read B-h1 (n2-3); stage A-h0(t+2) ----
#pragma unroll
    for (int n = 2; n < 4; n++) { LDB_F(bf[n][0], p, n, 0); LDB_F(bf[n][1], p, n, 1); }
    if (t + 2 < nkt) HSTAGE(t + 2, 0, 0);
    __builtin_amdgcn_s_barrier();
    __builtin_amdgcn_s_setprio(1);
#pragma unroll
    for (int m = 0; m < 4; m++)
#pragma unroll
      for (int n = 2; n < 4; n++) {
        acc[m][n] = __builtin_amdgcn_mfma_f32_16x16x32_bf16(af[m][0], bf[n][0], acc[m][n], 0, 0, 0);
        acc[m][n] = __builtin_amdgcn_mfma_f32_16x16x32_bf16(af[m][1], bf[n][1], acc[m][n], 0, 0, 0);
      }
    __builtin_amdgcn_s_setprio(0);
    __builtin_amdgcn_s_barrier();
    // ---- phase 2: ds_read A-h1 (m4-7, reuse af); stage B-h0(t+2) ----
#pragma unroll
    for (int m = 0; m < 4; m++) { LDA_F(af[m][0], p, m + 4, 0); LDA_F(af[m][1], p, m + 4, 1); }
    if (t + 2 < nkt) HSTAGE(t + 2, 1, 0);
    __builtin_amdgcn_s_barrier();
    __builtin_amdgcn_s_setprio(1);
#pragma unroll
    for (int m = 0; m < 4; m++)
#pragma unroll
      for (int n = 2; n < 4; n++) {
        acc[m + 4][n] = __builtin_amdgcn_mfma_f32_16x16x32_bf16(af[m][0], bf[n][0], acc[m + 4][n], 0, 0, 0);
        acc[m + 4][n] = __builtin_amdgcn_mfma_f32_16x16x32_bf16(af[m][1], bf[n][1], acc[m + 4][n], 0, 0, 0);
      }
    __builtin_amdgcn_s_setprio(0);
    __builtin_amdgcn_s_barrier();
    // ---- phase 3: stage B-h1(t+2); MFMA m4-7 x n0-1; boundary vmcnt + barrier ----
    if (t + 2 < nkt) HSTAGE(t + 2, 1, 1);
    __builtin_amdgcn_s_barrier();
    __builtin_amdgcn_s_setprio(1);
#pragma unroll
    for (int m = 0; m < 4; m++)
#pragma unroll
      for (int n = 0; n < 2; n++) {
        acc[m + 4][n] = __builtin_amdgcn_mfma_f32_16x16x32_bf16(af[m][0], bf[n][0], acc[m + 4][n], 0, 0, 0);
        acc[m + 4][n] = __builtin_amdgcn_mfma_f32_16x16x32_bf16(af[m][1], bf[n][1], acc[m + 4][n], 0, 0, 0);
      }
    __builtin_amdgcn_s_setprio(0);
    if (t < nkt - 2)       asm volatile("s_waitcnt vmcnt(6)" ::: "memory");
    else if (t == nkt - 2) asm volatile("s_waitcnt vmcnt(0)" ::: "memory");
    __builtin_amdgcn_s_barrier();
  }
#undef HSTAGE
#undef LDA_F
#undef LDB_F

  // epilogue: -0.5 * sum(relu(c)^2), wave-reduce, one atomic per wave
  float loc = 0.f;
#pragma unroll
  for (int i = 0; i < 8; i++)
#pragma unroll
    for (int j = 0; j < 4; j++)
#pragma unroll
      for (int r = 0; r < 4; r++) {
        float v = acc[i][j][r];
        loc += (v > 0.f) ? v * v : 0.f;
      }
#pragma unroll
  for (int mask = 32; mask; mask >>= 1) loc += __shfl_xor(loc, mask, 64);
  if (lane == 0) atomicAdd(out, -0.5f * loc);
}

// ---------------- scores: single-stage tile kernel (K=64 -> NO K-loop) ----------------
// grid (z=24, qt=16, kt=8): block = 128 q-rows x 256 k-cols of one head.
// Stage q-tile (16KB) + k-tile (32KB) ONCE via global_load_lds, ONE barrier, then pure
// register compute: per wave 64 MFMA + 128 exp2/lane, 32 independent (m,n) chains.
// Partial rowsums: shfl-reduce over 16 k-col lanes, atomicAdd (8 contenders/row).
// z % 8 -> XCD (linear id = (kt*16+qt)*24 + z, 24%8==0): 1.5MB/XCD working set.
__global__ __launch_bounds__(256) void score_tile(
    const u16* __restrict__ qB, const u16* __restrict__ kB, float* __restrict__ rowsum)
{
  __shared__ __align__(16) u16 qlds[128 * 64];   // 16 KB
  __shared__ __align__(16) u16 klds[256 * 64];   // 32 KB
  const int z = blockIdx.x, qt = blockIdx.y, kt = blockIdx.z;
  const int tid = threadIdx.x, lane = tid & 63, w = tid >> 6;
  const int l15 = lane & 15, lg = lane >> 4;

  // stage q: 1024 16-B chunks (4/thread); dst linear (chunk*16), src col pre-XOR'd
#pragma unroll
  for (int i = 0; i < 4; i++) {
    int c = i * 256 + tid;
    int r = c >> 3;
    int cb = ((c & 7) << 4) ^ ((r & 7) << 4);
    const char* src = (const char*)qB + ((size_t)z * 2048 + qt * 128 + r) * 128 + cb;
    __builtin_amdgcn_global_load_lds((const __attribute__((address_space(1))) void*)src,
        (__attribute__((address_space(3))) void*)((char*)qlds + c * 16), 16, 0, 0);
  }
  // stage k: 2048 chunks (8/thread)
#pragma unroll
  for (int i = 0; i < 8; i++) {
    int c = i * 256 + tid;
    int r = c >> 3;
    int cb = ((c & 7) << 4) ^ ((r & 7) << 4);
    const char* src = (const char*)kB + ((size_t)z * 2048 + kt * 256 + r) * 128 + cb;
    __builtin_amdgcn_global_load_lds((const __attribute__((address_space(1))) void*)src,
        (__attribute__((address_space(3))) void*)((char*)klds + c * 16), 16, 0, 0);
  }
  asm volatile("s_waitcnt vmcnt(0)" ::: "memory");
  __builtin_amdgcn_s_barrier();

  // B-frags: wave w owns k-cols w*64..+63 (4 n-frags x 2 k-slices)
  bf16x8 bf[4][2];
#pragma unroll
  for (int n = 0; n < 4; n++) {
    int row = w * 64 + n * 16 + l15;
    const char* base = (const char*)klds + row * 128;
    int sw = (row & 7) << 4;
    bf[n][0] = *(const bf16x8*)(base + ((lg * 16) ^ sw));
    bf[n][1] = *(const bf16x8*)(base + ((64 + lg * 16) ^ sw));
  }

  float rp[8][4];   // row-partial sumexp2: q-row m*16+lg*4+r over wave's 64 k-cols
#pragma unroll
  for (int m = 0; m < 8; m++)
#pragma unroll
    for (int r = 0; r < 4; r++) rp[m][r] = 0.f;

  const f32x4 zz = {0.f, 0.f, 0.f, 0.f};
#pragma unroll
  for (int m = 0; m < 8; m++) {
    int row = m * 16 + l15;
    const char* base = (const char*)qlds + row * 128;
    int sw = (row & 7) << 4;
    bf16x8 a0 = *(const bf16x8*)(base + ((lg * 16) ^ sw));
    bf16x8 a1 = *(const bf16x8*)(base + ((64 + lg * 16) ^ sw));
#pragma unroll
    for (int n = 0; n < 4; n++) {
      f32x4 s = zz;
      s = __builtin_amdgcn_mfma_f32_16x16x32_bf16(a0, bf[n][0], s, 0, 0, 0);
      s = __builtin_amdgcn_mfma_f32_16x16x32_bf16(a1, bf[n][1], s, 0, 0, 0);
      rp[m][0] += __builtin_amdgcn_exp2f(s[0]);
      rp[m][1] += __builtin_amdgcn_exp2f(s[1]);
      rp[m][2] += __builtin_amdgcn_exp2f(s[2]);
      rp[m][3] += __builtin_amdgcn_exp2f(s[3]);
    }
  }

  // reduce over the 16 k-col lanes (l15), then one atomic per (row)
#pragma unroll
  for (int m = 0; m < 8; m++)
#pragma unroll
    for (int r = 0; r < 4; r++) {
#pragma unroll
      for (int mask = 8; mask; mask >>= 1) rp[m][r] += __shfl_xor(rp[m][r], mask, 64);
    }
  if (l15 == 0) {
    float* rs = rowsum + (size_t)z * 2048 + qt * 128;
#pragma unroll
    for (int m = 0; m < 8; m++)
#pragma unroll
      for (int r = 0; r < 4; r++)
        atomicAdd(rs + m * 16 + lg * 4 + r, rp[m][r]);
  }
}

// ---------------- final: e_attn = -8*ln2 * sum(log2(rowsum)) ----------------
__global__ __launch_bounds__(256) void lse_reduce(
    const float* __restrict__ rowsum, float* __restrict__ out, int n)
{
  float v = 0.f;
  for (int i = blockIdx.x * blockDim.x + threadIdx.x; i < n; i += gridDim.x * blockDim.x)
    v += __builtin_amdgcn_logf(rowsum[i]);   // v_log_f32 = log2
#pragma unroll
  for (int mask = 32; mask; mask >>= 1) v += __shfl_xor(v, mask, 64);
  __shared__ float red[4];
  if ((threadIdx.x & 63) == 0) red[threadIdx.x >> 6] = v;
  __syncthreads();
  if (threadIdx.x == 0) {
    float t = red[0] + red[1] + red[2] + red[3];
    atomicAdd(out, -5.545177444479562f * t);   // -(1/beta)*ln2
  }
}

extern "C" void kernel_launch(void* const* d_in, const int* in_sizes, int n_in,
                              void* d_out, int out_size, void* d_ws, size_t ws_size,
                              hipStream_t stream)
{
  const float* g   = (const float*)d_in[0];
  const float* Wq  = (const float*)d_in[1];
  const float* Wk  = (const float*)d_in[2];
  const float* Whn = (const float*)d_in[3];
  float* out = (float*)d_out;
  char* ws = (char*)d_ws;

  u16* gB   = (u16*)(ws + OFF_GB);
  u16* wqB  = (u16*)(ws + OFF_WQB);
  u16* wkB  = (u16*)(ws + OFF_WKB);
  u16* whnB = (u16*)(ws + OFF_WHNB);
  u16* qB   = (u16*)(ws + OFF_QB);
  u16* kB   = (u16*)(ws + OFF_KB);
  float* rowsum = (float*)(ws + OFF_ROWSUM);

  (void)hipMemsetAsync(out, 0, sizeof(float), stream);
  (void)hipMemsetAsync(rowsum, 0, 49152 * sizeof(float), stream);

  convert_all<<<2048, 256, 0, stream>>>(g, Wq, Wk, Whn, gB, wqB, wkB, whnB);
  // q and k projections (XCD-chunked 1D grid: bn 0..5 -> q, 6..11 -> k)
  gemm_bt<<<384, 256, 0, stream>>>(gB, wqB, wkB, qB, kB, 1024);
  // Hopfield energy: 8-phase 256^2, XCD-chunked (R7 best config)
  hop_gemm8<<<256, 512, 0, stream>>>(gB, whnB, out);
  // scores: single-stage tiles + rowsum atomics, then logsumexp reduce
  score_tile<<<dim3(24, 16, 8), 256, 0, stream>>>(qB, kB, rowsum);
  lse_reduce<<<96, 256, 0, stream>>>(rowsum, out, 49152);
}

// Round 12
// 187.456 us; speedup vs baseline: 1.2350x; 1.0598x over previous
//
#include <hip/hip_runtime.h>
#include <hip/hip_bf16.h>

typedef __attribute__((ext_vector_type(4))) float f32x4;
typedef __attribute__((ext_vector_type(8))) short bf16x8;   // 8 bf16 = 4 VGPRs
typedef unsigned short u16;
typedef __attribute__((ext_vector_type(4))) u16 u16x4;

// Problem constants
// g [2,2048,1024] f32 ; Wq/Wk [12,64,1024] f32 ; Whn [4096,1024] f32 ; out = scalar f32

// workspace layout (bytes)
#define OFF_GB    ((size_t)0)                    // g bf16      [4096][1024]  8388608
#define OFF_WQB   ((size_t)8388608)              // (beta*log2e)*Wq bf16 [768][1024]
#define OFF_WKB   ((size_t)(8388608+1572864))    // Wk bf16      [768][1024]
#define OFF_WHNB  ((size_t)(8388608+2*1572864))  // Whn bf16    [4096][1024]  8388608
#define OFF_QB    (OFF_WHNB + 8388608)           // q bf16 [24][2048][64] per-head
#define OFF_KB    (OFF_QB + 6291456)             // k bf16 [24][2048][64] per-head
#define OFF_ROWSUM (OFF_KB + 6291456)            // f32 [32][49152] per-(kt,wave) rowsum partials

__device__ __forceinline__ u16 f2bf(float f) {
  union { float f; unsigned u; } x; x.f = f;
  unsigned u = x.u;
  u += 0x7fffu + ((u >> 16) & 1u);   // RNE
  return (u16)(u >> 16);
}

// ---------------- fused f32 -> bf16 conversion (beta*log2e folded into Wq) ----------------
__global__ __launch_bounds__(256) void convert_all(
    const float* __restrict__ g, const float* __restrict__ wq,
    const float* __restrict__ wk, const float* __restrict__ whn,
    u16* __restrict__ gB, u16* __restrict__ wqB, u16* __restrict__ wkB, u16* __restrict__ whnB)
{
  const int NG = 1048576;   // 4194304/4 float4 quads
  const int NW = 196608;    // 786432/4
  const int total = NG + 2 * NW + NG;
  for (int i = blockIdx.x * blockDim.x + threadIdx.x; i < total; i += gridDim.x * blockDim.x) {
    const float4* src; u16* dst; int j; float scale = 1.0f;
    if (i < NG)              { src = (const float4*)g;   dst = gB;   j = i; }
    else if (i < NG + NW)    { src = (const float4*)wq;  dst = wqB;  j = i - NG;
                               scale = 0.125f * 1.44269504089f; }   // beta * log2(e)
    else if (i < NG + 2*NW)  { src = (const float4*)wk;  dst = wkB;  j = i - NG - NW; }
    else                     { src = (const float4*)whn; dst = whnB; j = i - NG - 2*NW; }
    float4 v = src[j];
    u16x4 o;
    o.x = f2bf(v.x * scale); o.y = f2bf(v.y * scale);
    o.z = f2bf(v.z * scale); o.w = f2bf(v.w * scale);
    *(u16x4*)(dst + (size_t)j * 4) = o;
  }
}

// ---------------- q/k projection: 64x128 tiles, 768 blocks = EXACTLY 3/CU ----------------
// (was 128x128 / 384 blocks = 1.5/CU -> half the CUs ran 2 serialized rounds).
// XCD-chunked: xcd = bid&7 owns bm in [xcd*8, +8) x all 12 bn -> 1MB A + 1.5MB B per XCD L2.
// bn<6 -> Wq->qB, else Wk->kB; store bf16 into per-head layout [z][n][64]
__global__ __launch_bounds__(256) void gemm_bt(
    const u16* __restrict__ A, const u16* __restrict__ B0, const u16* __restrict__ B1,
    u16* __restrict__ C0, u16* __restrict__ C1, int K)
{
  __shared__ __align__(16) u16 lA[64 * 64];    // 8 KB
  __shared__ __align__(16) u16 lB[128 * 64];   // 16 KB
  const int tid = threadIdx.x;
  const int lane = tid & 63;
  const int w = tid >> 6;          // wave 0..3
  const int bid = blockIdx.x;
  const int xcd = bid & 7, idx = bid >> 3;          // idx 0..95
  const int bm = xcd * 8 + (idx & 7);               // 0..63 (64-row tiles)
  const int bn = idx >> 3;                          // 0..11 (128-col tiles)

  const u16* Bp; u16* Cp; int bcol0;
  if (bn < 6) { Bp = B0; Cp = C0; bcol0 = bn * 128; }
  else        { Bp = B1; Cp = C1; bcol0 = (bn - 6) * 128; }
  const int arow0 = bm * 64;
  const int wr = w >> 1, wc = w & 1;                // 2 M-groups x 2 N-groups
  const int l15 = lane & 15, lg = lane >> 4;

  f32x4 acc[2][4];
  const f32x4 zz = {0.f, 0.f, 0.f, 0.f};
#pragma unroll
  for (int m = 0; m < 2; m++)
#pragma unroll
    for (int n = 0; n < 4; n++) acc[m][n] = zz;

  // stage: A 64x64 (512 chunks, 2/thread) + B 128x64 (1024 chunks, 4/thread)
#define STAGE(KT) do {                                                                     \
    _Pragma("unroll")                                                                      \
    for (int i = 0; i < 2; i++) {                                                          \
      int c = i * 256 + tid;                                                               \
      int r = c >> 3;                                                                      \
      int cb = (((c & 7) ^ (r & 7)) << 4);                                                 \
      const char* src = (const char*)A + (((size_t)(arow0 + r)) * K + (KT) * 64) * 2 + cb; \
      __builtin_amdgcn_global_load_lds((const __attribute__((address_space(1))) void*)src, \
          (__attribute__((address_space(3))) void*)((char*)lA + c * 16), 16, 0, 0);        \
    }                                                                                      \
    _Pragma("unroll")                                                                      \
    for (int i = 0; i < 4; i++) {                                                          \
      int c = i * 256 + tid;                                                               \
      int r = c >> 3;                                                                      \
      int cb = (((c & 7) ^ (r & 7)) << 4);                                                 \
      const char* src = (const char*)Bp + (((size_t)(bcol0 + r)) * K + (KT) * 64) * 2 + cb;\
      __builtin_amdgcn_global_load_lds((const __attribute__((address_space(1))) void*)src, \
          (__attribute__((address_space(3))) void*)((char*)lB + c * 16), 16, 0, 0);        \
    }                                                                                      \
  } while (0)

  STAGE(0);
  const int nkt = K / 64;
  for (int kt = 0; kt < nkt; ++kt) {
    __syncthreads();
    bf16x8 a0[2], a1[2], b0[4], b1[4];
#pragma unroll
    for (int m = 0; m < 2; m++) {
      int row = wr * 32 + m * 16 + l15;
      const char* base = (const char*)lA + row * 128;
      int sw = (row & 7) << 4;
      a0[m] = *(const bf16x8*)(base + ((lg * 16) ^ sw));
      a1[m] = *(const bf16x8*)(base + ((64 + lg * 16) ^ sw));
    }
#pragma unroll
    for (int n = 0; n < 4; n++) {
      int row = wc * 64 + n * 16 + l15;
      const char* base = (const char*)lB + row * 128;
      int sw = (row & 7) << 4;
      b0[n] = *(const bf16x8*)(base + ((lg * 16) ^ sw));
      b1[n] = *(const bf16x8*)(base + ((64 + lg * 16) ^ sw));
    }
    __syncthreads();
    if (kt + 1 < nkt) STAGE(kt + 1);
#pragma unroll
    for (int m = 0; m < 2; m++)
#pragma unroll
      for (int n = 0; n < 4; n++) {
        acc[m][n] = __builtin_amdgcn_mfma_f32_16x16x32_bf16(a0[m], b0[n], acc[m][n], 0, 0, 0);
        acc[m][n] = __builtin_amdgcn_mfma_f32_16x16x32_bf16(a1[m], b1[n], acc[m][n], 0, 0, 0);
      }
  }
  // C/D layout (m89-verified): col = lane&15, row = (lane>>4)*4 + reg
  // per-head dst: row = b*2048+nn, col = h*64+d  ->  ((b*12+h)*2048 + nn)*64 + d
#pragma unroll
  for (int m = 0; m < 2; m++)
#pragma unroll
    for (int n = 0; n < 4; n++)
#pragma unroll
      for (int r = 0; r < 4; r++) {
        int row = arow0 + wr * 32 + m * 16 + lg * 4 + r;
        int col = bcol0 + wc * 64 + n * 16 + l15;
        size_t dst = ((((size_t)(row >> 11) * 12 + (col >> 6)) << 11) + (row & 2047)) * 64 + (col & 63);
        Cp[dst] = f2bf(acc[m][n][r]);
      }
#undef STAGE
}

// ---------------- Hopfield energy: 256x256-tile 8-phase GEMM (best known: 56.6us) ----------------
// XCD-chunked 1D grid (256 blocks): xcd = bid&7 owns a contiguous 4bm x 8bn chunk.
__global__ __launch_bounds__(512, 2) void hop_gemm8(
    const u16* __restrict__ A, const u16* __restrict__ Bm, float* __restrict__ out)
{
  __shared__ __align__(16) u16 lds[2][2][2][128][64];   // [buf][mat][half][row][col]
  const int tid = threadIdx.x;
  const int lane = tid & 63, w = tid >> 6;
  const int wr = w >> 2, wc = w & 3;
  const int l15 = lane & 15, lg = lane >> 4;
  const int bid = blockIdx.x;
  const int xcd = bid & 7, idx = bid >> 3;            // idx 0..31
  const int am0 = (((xcd >> 1) << 2) + (idx & 3)) * 256;   // bm 0..15
  const int bn0 = (((xcd & 1) << 3) + (idx >> 2)) * 256;   // bn 0..15
  constexpr int nkt = 16;   // K = 1024, BK = 64

  f32x4 acc[8][4];
  const f32x4 zz = {0.f, 0.f, 0.f, 0.f};
#pragma unroll
  for (int i = 0; i < 8; i++)
#pragma unroll
    for (int j = 0; j < 4; j++) acc[i][j] = zz;

#define HSTAGE(KT, MAT, H) do {                                                            \
    const u16* s_ = (MAT) ? Bm : A;                                                        \
    int rb_ = ((MAT) ? bn0 : am0) + (H) * 128;                                             \
    char* d0_ = (char*)&lds[(KT) & 1][(MAT)][(H)][0][0];                                   \
    _Pragma("unroll")                                                                      \
    for (int q_ = 0; q_ < 2; q_++) {                                                       \
      int r_ = q_ * 64 + (tid >> 3);                                                       \
      int cb_ = ((tid & 7) * 16) ^ ((r_ & 7) << 4);                                        \
      const char* g_ = (const char*)s_ + (size_t)(rb_ + r_) * 2048 + (KT) * 128 + cb_;     \
      __builtin_amdgcn_global_load_lds((const __attribute__((address_space(1))) void*)g_,  \
          (__attribute__((address_space(3))) void*)(d0_ + q_ * 8192 + tid * 16), 16, 0, 0);\
    }                                                                                      \
  } while (0)

#define LDA_F(DST, P, I, S) do {                                                           \
    int rh_ = ((I) & 3) * 32 + wr * 16 + l15;                                              \
    const char* b_ = (const char*)&lds[(P)][0][(I) >> 2][0][0] + rh_ * 128;                \
    DST = *(const bf16x8*)(b_ + (((S) * 64 + lg * 16) ^ ((rh_ & 7) << 4)));                \
  } while (0)
#define LDB_F(DST, P, J, S) do {                                                           \
    int rh_ = ((J) & 1) * 64 + wc * 16 + l15;                                              \
    const char* b_ = (const char*)&lds[(P)][1][(J) >> 1][0][0] + rh_ * 128;                \
    DST = *(const bf16x8*)(b_ + (((S) * 64 + lg * 16) ^ ((rh_ & 7) << 4)));                \
  } while (0)

  // prologue: tile0 all 4 halves, tile1 first 3 halves -> 14 loads; drain to 6 (tile0 done)
  HSTAGE(0, 0, 0); HSTAGE(0, 1, 0); HSTAGE(0, 1, 1); HSTAGE(0, 0, 1);
  HSTAGE(1, 0, 0); HSTAGE(1, 1, 0); HSTAGE(1, 1, 1);
  asm volatile("s_waitcnt vmcnt(6)" ::: "memory");
  __builtin_amdgcn_s_barrier();

  bf16x8 af[4][2], bf[4][2];

#pragma unroll 2
  for (int t = 0; t < nkt; ++t) {
    const int p = t & 1;
    // ---- phase 0: ds_read A-h0 (m0-3) + B-h0 (n0-1); stage A-h1(t+1) ----
#pragma unroll
    for (int m = 0; m < 4; m++) { LDA_F(af[m][0], p, m, 0); LDA_F(af[m][1], p, m, 1); }
#pragma unroll
    for (int n = 0; n < 2; n++) { LDB_F(bf[n][0], p, n, 0); LDB_F(bf[n][1], p, n, 1); }
    if (t + 1 < nkt) HSTAGE(t + 1, 0, 1);
    __builtin_amdgcn_s_barrier();
    __builtin_amdgcn_s_setprio(1);
#pragma unroll
    for (int m = 0; m < 4; m++)
#pragma unroll
      for (int n = 0; n < 2; n++) {
        acc[m][n] = __builtin_amdgcn_mfma_f32_16x16x32_bf16(af[m][0], bf[n][0], acc[m][n], 0, 0, 0);
        acc[m][n] = __builtin_amdgcn_mfma_f32_16x16x32_bf16(af[m][1], bf[n][1], acc[m][n], 0, 0, 0);
      }
    __builtin_amdgcn_s_setprio(0);
    __builtin_amdgcn_s_barrier();
    // ---- phase 1: ds_read B-h1 (n2-3); stage A-h0(t+2) ----
#pragma unroll
    for (int n = 2; n < 4; n++) { LDB_F(bf[n][0], p, n, 0); LDB_F(bf[n][1], p, n, 1); }
    if (t + 2 < nkt) HSTAGE(t + 2, 0, 0);
    __builtin_amdgcn_s_barrier();
    __builtin_amdgcn_s_setprio(1);
#pragma unroll
    for (int m = 0; m < 4; m++)
#pragma unroll
      for (int n = 2; n < 4; n++) {
        acc[m][n] = __builtin_amdgcn_mfma_f32_16x16x32_bf16(af[m][0], bf[n][0], acc[m][n], 0, 0, 0);
        acc[m][n] = __builtin_amdgcn_mfma_f32_16x16x32_bf16(af[m][1], bf[n][1], acc[m][n], 0, 0, 0);
      }
    __builtin_amdgcn_s_setprio(0);
    __builtin_amdgcn_s_barrier();
    // ---- phase 2: ds_read A-h1 (m4-7, reuse af); stage B-h0(t+2) ----
#pragma unroll
    for (int m = 0; m < 4; m++) { LDA_F(af[m][0], p, m + 4, 0); LDA_F(af[m][1], p, m + 4, 1); }
    if (t + 2 < nkt) HSTAGE(t + 2, 1, 0);
    __builtin_amdgcn_s_barrier();
    __builtin_amdgcn_s_setprio(1);
#pragma unroll
    for (int m = 0; m < 4; m++)
#pragma unroll
      for (int n = 2; n < 4; n++) {
        acc[m + 4][n] = __builtin_amdgcn_mfma_f32_16x16x32_bf16(af[m][0], bf[n][0], acc[m + 4][n], 0, 0, 0);
        acc[m + 4][n] = __builtin_amdgcn_mfma_f32_16x16x32_bf16(af[m][1], bf[n][1], acc[m + 4][n], 0, 0, 0);
      }
    __builtin_amdgcn_s_setprio(0);
    __builtin_amdgcn_s_barrier();
    // ---- phase 3: stage B-h1(t+2); MFMA m4-7 x n0-1; boundary vmcnt + barrier ----
    if (t + 2 < nkt) HSTAGE(t + 2, 1, 1);
    __builtin_amdgcn_s_barrier();
    __builtin_amdgcn_s_setprio(1);
#pragma unroll
    for (int m = 0; m < 4; m++)
#pragma unroll
      for (int n = 0; n < 2; n++) {
        acc[m + 4][n] = __builtin_amdgcn_mfma_f32_16x16x32_bf16(af[m][0], bf[n][0], acc[m + 4][n], 0, 0, 0);
        acc[m + 4][n] = __builtin_amdgcn_mfma_f32_16x16x32_bf16(af[m][1], bf[n][1], acc[m + 4][n], 0, 0, 0);
      }
    __builtin_amdgcn_s_setprio(0);
    if (t < nkt - 2)       asm volatile("s_waitcnt vmcnt(6)" ::: "memory");
    else if (t == nkt - 2) asm volatile("s_waitcnt vmcnt(0)" ::: "memory");
    __builtin_amdgcn_s_barrier();
  }
#undef HSTAGE
#undef LDA_F
#undef LDB_F

  // epilogue: -0.5 * sum(relu(c)^2), wave-reduce, one atomic per wave
  float loc = 0.f;
#pragma unroll
  for (int i = 0; i < 8; i++)
#pragma unroll
    for (int j = 0; j < 4; j++)
#pragma unroll
      for (int r = 0; r < 4; r++) {
        float v = acc[i][j][r];
        loc += (v > 0.f) ? v * v : 0.f;
      }
#pragma unroll
  for (int mask = 32; mask; mask >>= 1) loc += __shfl_xor(loc, mask, 64);
  if (lane == 0) atomicAdd(out, -0.5f * loc);
}

// ---------------- scores: single-stage tile kernel (K=64 -> NO K-loop) ----------------
// grid (z=24, qt=16, kt=8): block = 128 q-rows x 256 k-cols of one head.
// Stage q-tile (16KB) + k-tile (32KB) ONCE, ONE barrier, pure register compute.
// Partials written NON-ATOMICALLY to rowsum[kt*4+w][z*2048+row] (each wave owns its
// slice); lse_reduce sums the 32 slices. No memset, no atomics.
__global__ __launch_bounds__(256) void score_tile(
    const u16* __restrict__ qB, const u16* __restrict__ kB, float* __restrict__ rowsum)
{
  __shared__ __align__(16) u16 qlds[128 * 64];   // 16 KB
  __shared__ __align__(16) u16 klds[256 * 64];   // 32 KB
  const int z = blockIdx.x, qt = blockIdx.y, kt = blockIdx.z;
  const int tid = threadIdx.x, lane = tid & 63, w = tid >> 6;
  const int l15 = lane & 15, lg = lane >> 4;

  // stage q: 1024 16-B chunks (4/thread); dst linear, src col pre-XOR'd
#pragma unroll
  for (int i = 0; i < 4; i++) {
    int c = i * 256 + tid;
    int r = c >> 3;
    int cb = ((c & 7) << 4) ^ ((r & 7) << 4);
    const char* src = (const char*)qB + ((size_t)z * 2048 + qt * 128 + r) * 128 + cb;
    __builtin_amdgcn_global_load_lds((const __attribute__((address_space(1))) void*)src,
        (__attribute__((address_space(3))) void*)((char*)qlds + c * 16), 16, 0, 0);
  }
  // stage k: 2048 chunks (8/thread)
#pragma unroll
  for (int i = 0; i < 8; i++) {
    int c = i * 256 + tid;
    int r = c >> 3;
    int cb = ((c & 7) << 4) ^ ((r & 7) << 4);
    const char* src = (const char*)kB + ((size_t)z * 2048 + kt * 256 + r) * 128 + cb;
    __builtin_amdgcn_global_load_lds((const __attribute__((address_space(1))) void*)src,
        (__attribute__((address_space(3))) void*)((char*)klds + c * 16), 16, 0, 0);
  }
  asm volatile("s_waitcnt vmcnt(0)" ::: "memory");
  __builtin_amdgcn_s_barrier();

  // B-frags: wave w owns k-cols w*64..+63 (4 n-frags x 2 k-slices)
  bf16x8 bf[4][2];
#pragma unroll
  for (int n = 0; n < 4; n++) {
    int row = w * 64 + n * 16 + l15;
    const char* base = (const char*)klds + row * 128;
    int sw = (row & 7) << 4;
    bf[n][0] = *(const bf16x8*)(base + ((lg * 16) ^ sw));
    bf[n][1] = *(const bf16x8*)(base + ((64 + lg * 16) ^ sw));
  }

  float rp[8][4];   // row-partial sumexp2: q-row m*16+lg*4+r over wave's 64 k-cols
#pragma unroll
  for (int m = 0; m < 8; m++)
#pragma unroll
    for (int r = 0; r < 4; r++) rp[m][r] = 0.f;

  const f32x4 zz = {0.f, 0.f, 0.f, 0.f};
#pragma unroll
  for (int m = 0; m < 8; m++) {
    int row = m * 16 + l15;
    const char* base = (const char*)qlds + row * 128;
    int sw = (row & 7) << 4;
    bf16x8 a0 = *(const bf16x8*)(base + ((lg * 16) ^ sw));
    bf16x8 a1 = *(const bf16x8*)(base + ((64 + lg * 16) ^ sw));
#pragma unroll
    for (int n = 0; n < 4; n++) {
      f32x4 s = zz;
      s = __builtin_amdgcn_mfma_f32_16x16x32_bf16(a0, bf[n][0], s, 0, 0, 0);
      s = __builtin_amdgcn_mfma_f32_16x16x32_bf16(a1, bf[n][1], s, 0, 0, 0);
      rp[m][0] += __builtin_amdgcn_exp2f(s[0]);
      rp[m][1] += __builtin_amdgcn_exp2f(s[1]);
      rp[m][2] += __builtin_amdgcn_exp2f(s[2]);
      rp[m][3] += __builtin_amdgcn_exp2f(s[3]);
    }
  }

  // reduce over the 16 k-col lanes (l15); wave's 4 lg-lanes write 128 distinct rows
#pragma unroll
  for (int m = 0; m < 8; m++)
#pragma unroll
    for (int r = 0; r < 4; r++) {
#pragma unroll
      for (int mask = 8; mask; mask >>= 1) rp[m][r] += __shfl_xor(rp[m][r], mask, 64);
    }
  if (l15 == 0) {
    // each wave covers distinct k-cols -> per-(kt,wave) slice, summed in lse_reduce
    float* rs = rowsum + ((size_t)(kt * 4 + w) * 24 + z) * 2048 + qt * 128;
#pragma unroll
    for (int m = 0; m < 8; m++)
#pragma unroll
      for (int r = 0; r < 4; r++)
        rs[m * 16 + lg * 4 + r] = rp[m][r];
  }
}

// ---------------- final: e_attn = -8*ln2 * sum(log2( sum_32slices rowsum )) ----------------
__global__ __launch_bounds__(256) void lse_reduce(
    const float* __restrict__ rowsum, float* __restrict__ out, int n)
{
  float v = 0.f;
  for (int i = blockIdx.x * blockDim.x + threadIdx.x; i < n; i += gridDim.x * blockDim.x) {
    float s = 0.f;
#pragma unroll
    for (int kt = 0; kt < 32; kt++) s += rowsum[(size_t)kt * 49152 + i];
    v += __builtin_amdgcn_logf(s);   // v_log_f32 = log2
  }
#pragma unroll
  for (int mask = 32; mask; mask >>= 1) v += __shfl_xor(v, mask, 64);
  __shared__ float red[4];
  if ((threadIdx.x & 63) == 0) red[threadIdx.x >> 6] = v;
  __syncthreads();
  if (threadIdx.x == 0) {
    float t = red[0] + red[1] + red[2] + red[3];
    atomicAdd(out, -5.545177444479562f * t);   // -(1/beta)*ln2
  }
}

extern "C" void kernel_launch(void* const* d_in, const int* in_sizes, int n_in,
                              void* d_out, int out_size, void* d_ws, size_t ws_size,
                              hipStream_t stream)
{
  const float* g   = (const float*)d_in[0];
  const float* Wq  = (const float*)d_in[1];
  const float* Wk  = (const float*)d_in[2];
  const float* Whn = (const float*)d_in[3];
  float* out = (float*)d_out;
  char* ws = (char*)d_ws;

  u16* gB   = (u16*)(ws + OFF_GB);
  u16* wqB  = (u16*)(ws + OFF_WQB);
  u16* wkB  = (u16*)(ws + OFF_WKB);
  u16* whnB = (u16*)(ws + OFF_WHNB);
  u16* qB   = (u16*)(ws + OFF_QB);
  u16* kB   = (u16*)(ws + OFF_KB);
  float* rowsum = (float*)(ws + OFF_ROWSUM);   // 32 x 49152 f32 = 6.3 MB

  (void)hipMemsetAsync(out, 0, sizeof(float), stream);

  convert_all<<<2048, 256, 0, stream>>>(g, Wq, Wk, Whn, gB, wqB, wkB, whnB);
  // q and k projections: 64x128 tiles, 768 blocks = 3/CU exact, XCD-chunked
  gemm_bt<<<768, 256, 0, stream>>>(gB, wqB, wkB, qB, kB, 1024);
  // Hopfield energy: 8-phase 256^2, XCD-chunked (best known config)
  hop_gemm8<<<256, 512, 0, stream>>>(gB, whnB, out);
  // scores: single-stage tiles, non-atomic per-(kt,wave) partials, then logsumexp reduce
  score_tile<<<dim3(24, 16, 8), 256, 0, stream>>>(qB, kB, rowsum);
  lse_reduce<<<96, 256, 0, stream>>>(rowsum, out, 49152);
}